// Round 1
// baseline (98.054 us; speedup 1.0000x reference)
//
#include <hip/hip_runtime.h>
#include <math.h>

#define NXC 432
#define NYC 496
#define CELLS (NYC * NXC)          // 214272
#define BATCH 4
#define PTOT 48000
#define NPT 32
#define EPSC 1e-3f

// ---------------------------------------------------------------------------
// Kernel 1: per-pillar fused PFN1 + PFN2 + BN + ReLU + max + attention mix.
// One wave (64 lanes) per pillar; lane = output channel f.
// Writes comb[p][f] = f1*a0 + f2*(1-a0) and map[b*CELLS + lin] = p.
// ---------------------------------------------------------------------------
__global__ __launch_bounds__(256) void pfe_kernel(
    const float* __restrict__ pillars, const float* __restrict__ w1,
    const float* __restrict__ bn1, const float* __restrict__ w2,
    const float* __restrict__ bn2, const float* __restrict__ wf1,
    const float* __restrict__ wf2, const float* __restrict__ fbn1,
    const float* __restrict__ fbn2, const int* __restrict__ coords,
    const int* __restrict__ num_points, float* __restrict__ comb,
    int* __restrict__ map)
{
    __shared__ float lds[4 * NPT * 8];   // 4 pillars x 32 pts x 8 feats = 4 KB
    const int tid  = threadIdx.x;
    const int wave = tid >> 6;
    const int lane = tid & 63;
    const int pbase = blockIdx.x * 4;

    // cooperative load: 4 pillars = 1024 floats = 256 float4 (1 per thread)
    {
        const float4* src = (const float4*)(pillars + (size_t)pbase * (NPT * 8));
        ((float4*)lds)[tid] = src[tid];
    }
    __syncthreads();

    const int p = pbase + wave;
    const float* pl = lds + wave * (NPT * 8);

    // --- mean xyz over all 32 points (reference does NOT mask), / num_points
    float sx = 0.f, sy = 0.f, sz = 0.f;
    if (lane < NPT) {
        sx = pl[lane * 8 + 0];
        sy = pl[lane * 8 + 1];
        sz = pl[lane * 8 + 2];
    }
#pragma unroll
    for (int off = 32; off; off >>= 1) {
        sx += __shfl_xor(sx, off);
        sy += __shfl_xor(sy, off);
        sz += __shfl_xor(sz, off);
    }
    const float inv_np = 1.0f / (float)num_points[p];
    const float mxm = sx * inv_np, mym = sy * inv_np, mzm = sz * inv_np;

    const int c1 = coords[p * 4 + 1], c2 = coords[p * 4 + 2], c3 = coords[p * 4 + 3];
    const float cx = c3 * 0.16f + 0.08f;
    const float cy = c2 * 0.16f + (-39.6f);
    const float cz = c1 * 4.0f  + (-1.0f);

    const int f = lane;

    // --- fold PFN1: h1 = x*AX + y*AY + z*AZ + i*AI + C0 (BN scale folded in)
    const float g1 = bn1[f], be1 = bn1[64 + f], bm1 = bn1[128 + f], bv1 = bn1[192 + f];
    const float s1 = g1 * rsqrtf(bv1 + EPSC);
    const float w10 = w1[f],        w11 = w1[64 + f],  w12 = w1[128 + f], w13 = w1[192 + f];
    const float w14 = w1[256 + f],  w15 = w1[320 + f], w16 = w1[384 + f];
    const float w17 = w1[448 + f],  w18 = w1[512 + f], w19 = w1[576 + f];
    const float AX = (w10 + w14 + w17) * s1;
    const float AY = (w11 + w15 + w18) * s1;
    const float AZ = (w12 + w16 + w19) * s1;
    const float AI = w13 * s1;
    const float C0 = be1 - bm1 * s1
                   - (mxm * w14 + mym * w15 + mzm * w16) * s1
                   - (cx * w17 + cy * w18 + cz * w19) * s1;

    // --- fold PFN2: h2 = sum_c p[n,c]*Bc + C2
    const float g2 = bn2[f], be2 = bn2[64 + f], bm2 = bn2[128 + f], bv2 = bn2[192 + f];
    const float s2 = g2 * rsqrtf(bv2 + EPSC);
    const float B0 = w2[f] * s2,        B1 = w2[64 + f] * s2;
    const float B2 = w2[128 + f] * s2,  B3 = w2[192 + f] * s2;
    const float B4 = w2[256 + f] * s2,  B5 = w2[320 + f] * s2;
    const float B6 = w2[384 + f] * s2,  B7 = w2[448 + f] * s2;
    const float C2 = be2 - bm2 * s2;

    float max1 = -1e30f, max2 = -1e30f;
#pragma unroll 8
    for (int n = 0; n < NPT; n++) {
        const float4 a  = *(const float4*)(pl + n * 8);      // x,y,z,i (broadcast)
        const float4 q  = *(const float4*)(pl + n * 8 + 4);  // feats 4..7
        const float h1 = fmaf(a.x, AX, fmaf(a.y, AY, fmaf(a.z, AZ, fmaf(a.w, AI, C0))));
        max1 = fmaxf(max1, h1);
        const float h2 = fmaf(a.x, B0, fmaf(a.y, B1, fmaf(a.z, B2, fmaf(a.w, B3,
                        fmaf(q.x, B4, fmaf(q.y, B5, fmaf(q.z, B6, fmaf(q.w, B7, C2))))))));
        max2 = fmaxf(max2, h2);
    }
    // relu(bn(h)).max(n) == max(0, max_n h')  (BN affine already folded)
    const float f1v = fmaxf(max1, 0.f);
    const float f2v = fmaxf(max2, 0.f);

    // --- attention scalars: s = bn(dot(f, wf))
    float d1 = f1v * wf1[f];
    float d2 = f2v * wf2[f];
#pragma unroll
    for (int off = 32; off; off >>= 1) {
        d1 += __shfl_xor(d1, off);
        d2 += __shfl_xor(d2, off);
    }
    const float sc1 = (d1 - fbn1[2]) * (fbn1[0] * rsqrtf(fbn1[3] + EPSC)) + fbn1[1];
    const float sc2 = (d2 - fbn2[2]) * (fbn2[0] * rsqrtf(fbn2[3] + EPSC)) + fbn2[1];
    const float a0 = 1.0f / (1.0f + expf(sc2 - sc1));   // softmax weight of branch 1

    comb[p * 64 + f] = fmaf(f1v - f2v, a0, f2v);        // f1*a0 + f2*(1-a0)

    if (lane == 0) {
        const int lin  = c1 + c2 * NXC + c3;
        const int bidx = coords[p * 4 + 0];
        map[bidx * CELLS + lin] = p;
    }
}

// ---------------------------------------------------------------------------
// Kernel 2: dense emit. One thread per BEV cell; writes all 64 channels.
// Coalesced across x; every output element written exactly once.
// ---------------------------------------------------------------------------
__global__ __launch_bounds__(256) void emit_kernel(
    const int* __restrict__ map, const float* __restrict__ comb,
    float* __restrict__ out)
{
    const int cell = blockIdx.x * 256 + threadIdx.x;   // < BATCH*CELLS
    const int b = cell / CELLS;
    const int L = cell - b * CELLS;
    const int m = map[cell];

    const float sel = (m < 0) ? 0.f : 1.f;
    const int  mm   = (m < 0) ? 0   : m;
    const float* c  = comb + mm * 64;
    float* o = out + (b * 64) * CELLS + L;

#pragma unroll
    for (int fq = 0; fq < 16; fq++) {
        const float4 v = *(const float4*)(c + fq * 4);
        __builtin_nontemporal_store(v.x * sel, o + (fq * 4 + 0) * CELLS);
        __builtin_nontemporal_store(v.y * sel, o + (fq * 4 + 1) * CELLS);
        __builtin_nontemporal_store(v.z * sel, o + (fq * 4 + 2) * CELLS);
        __builtin_nontemporal_store(v.w * sel, o + (fq * 4 + 3) * CELLS);
    }
}

extern "C" void kernel_launch(void* const* d_in, const int* in_sizes, int n_in,
                              void* d_out, int out_size, void* d_ws, size_t ws_size,
                              hipStream_t stream) {
    const float* pillars = (const float*)d_in[0];
    const float* w1      = (const float*)d_in[1];
    const float* bn1     = (const float*)d_in[2];
    const float* w2      = (const float*)d_in[3];
    const float* bn2     = (const float*)d_in[4];
    const float* wf1     = (const float*)d_in[5];
    const float* wf2     = (const float*)d_in[6];
    const float* fbn1    = (const float*)d_in[7];
    const float* fbn2    = (const float*)d_in[8];
    const int*   coords  = (const int*)d_in[9];
    const int*   nump    = (const int*)d_in[10];
    float* out = (float*)d_out;

    int*   map  = (int*)d_ws;
    float* comb = (float*)((char*)d_ws + (size_t)BATCH * CELLS * 4);
    // ws usage: map 3.43 MB + comb 12.29 MB = 15.72 MB

    hipMemsetAsync(map, 0xFF, (size_t)BATCH * CELLS * 4, stream);  // all -1
    pfe_kernel<<<PTOT / 4, 256, 0, stream>>>(pillars, w1, bn1, w2, bn2,
                                             wf1, wf2, fbn1, fbn2,
                                             coords, nump, comb, map);
    emit_kernel<<<(BATCH * CELLS) / 256, 256, 0, stream>>>(map, comb, out);
}